// Round 1
// baseline (266.839 us; speedup 1.0000x reference)
//
#include <hip/hip_runtime.h>
#include <hip/hip_bf16.h>

#define NROWS 8192
#define NDIM  256
#define KNN   8
#define JSPLIT 4
#define JRANGE (NROWS / JSPLIT)

typedef __attribute__((ext_vector_type(8))) short bf16x8;
typedef __attribute__((ext_vector_type(4))) float f32x4;

// ---- workspace layout (bytes) ----
#define WS_EBF    0                                   // 8192*256*2   = 4 MiB
#define WS_SQN    (4*1024*1024)                       // 8192*4       = 32 KiB
#define WS_KNN    (WS_SQN + 32*1024)                  // 8192*4*8*4   = 1 MiB
#define WS_COL    (WS_KNN + NROWS*JSPLIT*KNN*4)       // 256*4        = 1 KiB
#define WS_ACC    (WS_COL + 1024)                     // 3 floats (sum8, S2, Q)

// Convert e -> bf16 and compute per-row squared norms (fp32, exact).
// One wave per row: lane l loads dims 4l..4l+3.
__global__ void k_prep(const float* __restrict__ e,
                       ushort* __restrict__ ebf,
                       float* __restrict__ sqn) {
  const int lane = threadIdx.x & 63;
  const int row  = blockIdx.x * (blockDim.x >> 6) + (threadIdx.x >> 6);
  const float4 v = *reinterpret_cast<const float4*>(e + row * NDIM + lane * 4);
  ushort4 o;
  {
    __hip_bfloat16 b0 = __float2bfloat16(v.x);
    __hip_bfloat16 b1 = __float2bfloat16(v.y);
    __hip_bfloat16 b2 = __float2bfloat16(v.z);
    __hip_bfloat16 b3 = __float2bfloat16(v.w);
    o.x = *reinterpret_cast<ushort*>(&b0);
    o.y = *reinterpret_cast<ushort*>(&b1);
    o.z = *reinterpret_cast<ushort*>(&b2);
    o.w = *reinterpret_cast<ushort*>(&b3);
  }
  *reinterpret_cast<ushort4*>(ebf + row * NDIM + lane * 4) = o;
  float acc = v.x*v.x + v.y*v.y + v.z*v.z + v.w*v.w;
  #pragma unroll
  for (int off = 32; off > 0; off >>= 1) acc += __shfl_down(acc, off);
  if (lane == 0) sqn[row] = acc;
}

// Column sums (for ref_std). 32 blocks x 256 rows each; coalesced across d.
__global__ void k_colsum(const float* __restrict__ e, float* __restrict__ colsum) {
  const int d  = threadIdx.x;
  const int r0 = blockIdx.x * 256;
  float s = 0.f;
  for (int r = 0; r < 256; ++r) s += e[(r0 + r) * NDIM + d];
  atomicAdd(&colsum[d], s);
}

// Main fused Gram + top-8 kernel. One wave per (16-row tile, column split).
__launch_bounds__(64)
__global__ void k_main(const ushort* __restrict__ eb,
                       const float* __restrict__ sqn,
                       float* __restrict__ knn_out) {
  const int lane = threadIdx.x;
  const int lcol = lane & 15;
  const int lgrp = lane >> 4;
  const int rbase  = blockIdx.x * 16;
  const int split  = blockIdx.y;
  const int jbase0 = split * JRANGE;

  // A fragments for this wave's 16 rows, all of K=256 (8 chunks of K=32).
  bf16x8 a[8];
  #pragma unroll
  for (int kk = 0; kk < 8; ++kk)
    a[kk] = *reinterpret_cast<const bf16x8*>(eb + (rbase + lcol) * NDIM + kk * 32 + lgrp * 8);

  // fp32 norms for the 4 C-rows this lane owns (row = lgrp*4 + rg).
  float nrow[4];
  #pragma unroll
  for (int rg = 0; rg < 4; ++rg)
    nrow[rg] = sqn[rbase + lgrp * 4 + rg];

  // Per-lane sorted top-8 lists (ascending), one per owned C-row.
  float m[4][KNN];
  #pragma unroll
  for (int rg = 0; rg < 4; ++rg) {
    #pragma unroll
    for (int i = 0; i < KNN; ++i) m[rg][i] = 1e30f;
  }

  for (int jb = jbase0; jb < jbase0 + JRANGE; jb += 16) {
    bf16x8 b[8];
    #pragma unroll
    for (int kk = 0; kk < 8; ++kk)
      b[kk] = *reinterpret_cast<const bf16x8*>(eb + (jb + lcol) * NDIM + kk * 32 + lgrp * 8);
    f32x4 acc = {0.f, 0.f, 0.f, 0.f};
    #pragma unroll
    for (int kk = 0; kk < 8; ++kk)
      acc = __builtin_amdgcn_mfma_f32_16x16x32_bf16(a[kk], b[kk], acc, 0, 0, 0);
    const float ncol = sqn[jb + lcol];
    #pragma unroll
    for (int rg = 0; rg < 4; ++rg) {
      float sq = fmaxf(nrow[rg] + ncol - 2.0f * acc[rg], 0.0f);
      if (sq < m[rg][KNN - 1]) {
        // sorted insert: r_i = min(m_i, carry); carry = max(m_i, carry)
        float carry = sq;
        #pragma unroll
        for (int k = 0; k < KNN; ++k) {
          float mi = m[rg][k];
          m[rg][k] = fminf(mi, carry);
          carry    = fmaxf(mi, carry);
        }
      }
    }
  }

  // Merge the 16 per-lane lists for each row: 8x min-extraction via shfl_xor.
  const unsigned long long gmask = 0xFFFFULL << (lgrp * 16);
  #pragma unroll
  for (int rg = 0; rg < 4; ++rg) {
    const int row = rbase + lgrp * 4 + rg;
    #pragma unroll
    for (int t = 0; t < KNN; ++t) {
      float c  = m[rg][0];
      float mn = c;
      mn = fminf(mn, __shfl_xor(mn, 1));
      mn = fminf(mn, __shfl_xor(mn, 2));
      mn = fminf(mn, __shfl_xor(mn, 4));
      mn = fminf(mn, __shfl_xor(mn, 8));
      unsigned long long ball = __ballot(c == mn) & gmask;
      int owner = __ffsll((unsigned long long)ball) - 1;
      if (lane == owner) {
        #pragma unroll
        for (int k = 0; k < KNN - 1; ++k) m[rg][k] = m[rg][k + 1];
        m[rg][KNN - 1] = 1e30f;
      }
      if (lcol == t) knn_out[(row * JSPLIT + split) * KNN + t] = mn;
    }
  }
}

// Merge JSPLIT sorted-8 lists per row -> sum of global 8 smallest; reduce
// sum8 and S2; block 0 also reduces Q = sum of colsum^2.
__global__ void k_final(const float* __restrict__ knn,
                        const float* __restrict__ sqn,
                        const float* __restrict__ colsum,
                        float* __restrict__ gacc) {
  const int tid = threadIdx.x;
  const int row = blockIdx.x * blockDim.x + tid;
  float m[KNN];
  #pragma unroll
  for (int i = 0; i < KNN; ++i) m[i] = 1e30f;
  const float* p = knn + row * (JSPLIT * KNN);
  for (int i = 0; i < JSPLIT * KNN; ++i) {
    float v = p[i];
    if (v < m[KNN - 1]) {
      float carry = v;
      #pragma unroll
      for (int k = 0; k < KNN; ++k) {
        float mi = m[k];
        m[k]  = fminf(mi, carry);
        carry = fmaxf(mi, carry);
      }
    }
  }
  float rs = 0.f;
  #pragma unroll
  for (int i = 0; i < KNN; ++i) rs += m[i];
  float s2 = sqn[row];

  __shared__ float red[2][4];
  #pragma unroll
  for (int off = 32; off > 0; off >>= 1) {
    rs += __shfl_down(rs, off);
    s2 += __shfl_down(s2, off);
  }
  if ((tid & 63) == 0) { red[0][tid >> 6] = rs; red[1][tid >> 6] = s2; }
  __syncthreads();
  if (tid == 0) {
    atomicAdd(&gacc[0], red[0][0] + red[0][1] + red[0][2] + red[0][3]);
    atomicAdd(&gacc[1], red[1][0] + red[1][1] + red[1][2] + red[1][3]);
  }
  if (blockIdx.x == 0) {
    float cs = colsum[tid];
    float q = cs * cs;
    #pragma unroll
    for (int off = 32; off > 0; off >>= 1) q += __shfl_down(q, off);
    __syncthreads();
    if ((tid & 63) == 0) red[0][tid >> 6] = q;
    __syncthreads();
    if (tid == 0) atomicAdd(&gacc[2], red[0][0] + red[0][1] + red[0][2] + red[0][3]);
  }
}

__global__ void k_out(const float* __restrict__ gacc, float* __restrict__ out) {
  if (threadIdx.x == 0 && blockIdx.x == 0) {
    float sum8 = gacc[0];
    float S2   = gacc[1];
    float Q    = gacc[2];
    float ref_var = (S2 - Q / (float)NROWS) / ((float)NDIM * (float)(NROWS - 1));
    out[0] = (sum8 / (float)(NROWS * KNN)) / ref_var;
  }
}

extern "C" void kernel_launch(void* const* d_in, const int* in_sizes, int n_in,
                              void* d_out, int out_size, void* d_ws, size_t ws_size,
                              hipStream_t stream) {
  const float* e = (const float*)d_in[0];
  char* ws = (char*)d_ws;
  ushort* ebf   = (ushort*)(ws + WS_EBF);
  float* sqn    = (float*)(ws + WS_SQN);
  float* knn    = (float*)(ws + WS_KNN);
  float* colsum = (float*)(ws + WS_COL);
  float* gacc   = (float*)(ws + WS_ACC);
  float* out    = (float*)d_out;

  // zero the atomic accumulators (colsum + gacc) every launch — harness does
  // not re-poison/restore ws between timed replays.
  hipMemsetAsync(ws + WS_COL, 0, 2048, stream);

  hipLaunchKernelGGL(k_prep,   dim3(NROWS / 4), dim3(256), 0, stream, e, ebf, sqn);
  hipLaunchKernelGGL(k_colsum, dim3(32),        dim3(256), 0, stream, e, colsum);
  hipLaunchKernelGGL(k_main,   dim3(NROWS / 16, JSPLIT), dim3(64), 0, stream, ebf, sqn, knn);
  hipLaunchKernelGGL(k_final,  dim3(NROWS / 256), dim3(256), 0, stream, knn, sqn, colsum, gacc);
  hipLaunchKernelGGL(k_out,    dim3(1), dim3(1), 0, stream, gacc, out);
}

// Round 2
// 131.362 us; speedup vs baseline: 2.0313x; 2.0313x over previous
//
#include <hip/hip_runtime.h>
#include <hip/hip_bf16.h>

#define NROWS 8192
#define NDIM  256
#define KNN   8
#define TCOLS 16

typedef __attribute__((ext_vector_type(8))) short bf16x8;
typedef __attribute__((ext_vector_type(4))) float f32x4;

// ---- workspace layout (bytes) ----
#define WS_EBF 0                        // 8192*256*2 = 4 MiB
#define WS_SQN (4*1024*1024)            // 32 KiB
#define WS_COL (WS_SQN + 32*1024)       // 1 KiB (colsum)
#define WS_ACC (WS_COL + 1024)          // 1 KiB (gacc: sum8, S2, Q)
#define WS_KNN (WS_ACC + 1024)          // NROWS*jsplit*KNN*4 (2 MiB @ jsplit=8)

// Convert e -> bf16 and compute per-row squared norms (fp32, exact).
__global__ void k_prep(const float* __restrict__ e,
                       ushort* __restrict__ ebf,
                       float* __restrict__ sqn) {
  const int lane = threadIdx.x & 63;
  const int row  = blockIdx.x * (blockDim.x >> 6) + (threadIdx.x >> 6);
  const float4 v = *reinterpret_cast<const float4*>(e + row * NDIM + lane * 4);
  ushort4 o;
  {
    __hip_bfloat16 b0 = __float2bfloat16(v.x);
    __hip_bfloat16 b1 = __float2bfloat16(v.y);
    __hip_bfloat16 b2 = __float2bfloat16(v.z);
    __hip_bfloat16 b3 = __float2bfloat16(v.w);
    o.x = *reinterpret_cast<ushort*>(&b0);
    o.y = *reinterpret_cast<ushort*>(&b1);
    o.z = *reinterpret_cast<ushort*>(&b2);
    o.w = *reinterpret_cast<ushort*>(&b3);
  }
  *reinterpret_cast<ushort4*>(ebf + row * NDIM + lane * 4) = o;
  float acc = v.x*v.x + v.y*v.y + v.z*v.z + v.w*v.w;
  #pragma unroll
  for (int off = 32; off > 0; off >>= 1) acc += __shfl_down(acc, off);
  if (lane == 0) sqn[row] = acc;
}

// Column sums (for ref_std).
__global__ void k_colsum(const float* __restrict__ e, float* __restrict__ colsum) {
  const int d  = threadIdx.x;
  const int r0 = blockIdx.x * 256;
  float s = 0.f;
  for (int r = 0; r < 256; ++r) s += e[(r0 + r) * NDIM + d];
  atomicAdd(&colsum[d], s);
}

// Fused Gram + top-8. Block = 4 waves x 16 rows = 64 rows; B tiles staged in
// LDS via global_load_lds (linear dest, inverse-swizzled source) and read
// back with the matching XOR swizzle (conflict-free ds_read_b128).
__launch_bounds__(256)
__global__ void k_main(const ushort* __restrict__ eb,
                       const float* __restrict__ sqn,
                       float* __restrict__ knn_out,
                       int jrange, int jsplit) {
  __shared__ ushort lbuf[2][TCOLS * NDIM];   // 2 x 8 KiB
  __shared__ float  lsqn[2048];              // up to 8 KiB

  const int tid  = threadIdx.x;
  const int lane = tid & 63;
  const int wv   = tid >> 6;
  const int lcol = lane & 15;
  const int lgrp = lane >> 4;
  const int wrow = blockIdx.x * 64 + wv * 16;
  const int split  = blockIdx.y;
  const int jbase0 = split * jrange;

  // A fragments: this wave's 16 rows, K=256 as 8 chunks of 32.
  bf16x8 a[8];
  #pragma unroll
  for (int kk = 0; kk < 8; ++kk)
    a[kk] = *reinterpret_cast<const bf16x8*>(eb + (wrow + lcol) * NDIM + kk * 32 + lgrp * 8);

  float nrow[4];
  #pragma unroll
  for (int rg = 0; rg < 4; ++rg) nrow[rg] = sqn[wrow + lgrp * 4 + rg];

  float m[4][KNN];
  #pragma unroll
  for (int rg = 0; rg < 4; ++rg)
    #pragma unroll
    for (int i = 0; i < KNN; ++i) m[rg][i] = 1e30f;

  const int wbyte = (tid & ~63) * 16;  // wave-uniform LDS base offset
  auto stage = [&](int bufi, int jb) {
    #pragma unroll
    for (int s = 0; s < 2; ++s) {
      const int o     = tid * 16 + s * 4096;            // linear LDS byte
      const int col   = o >> 9;                          // 512 B per column row
      const int inner = (o & 511) ^ ((col & 7) << 4);    // inverse swizzle on SOURCE
      const ushort* src = eb + (jb + col) * NDIM + (inner >> 1);
      __builtin_amdgcn_global_load_lds(
          (const __attribute__((address_space(1))) void*)src,
          (__attribute__((address_space(3))) void*)(
              reinterpret_cast<char*>(&lbuf[bufi][0]) + wbyte + s * 4096),
          16, 0, 0);
    }
  };

  for (int i = tid; i < jrange; i += 256) lsqn[i] = sqn[jbase0 + i];
  stage(0, jbase0);
  asm volatile("s_waitcnt vmcnt(0)" ::: "memory");
  __syncthreads();

  const int nIter = jrange / TCOLS;
  int buf = 0;
  for (int it = 0; it < nIter; ++it) {
    if (it + 1 < nIter) stage(buf ^ 1, jbase0 + (it + 1) * TCOLS);

    bf16x8 b[8];
    #pragma unroll
    for (int kk = 0; kk < 8; ++kk) {
      const int rb = lcol * 512 + ((kk * 64 + lgrp * 16) ^ ((lcol & 7) << 4));
      b[kk] = *reinterpret_cast<const bf16x8*>(
                  reinterpret_cast<const char*>(&lbuf[buf][0]) + rb);
    }
    f32x4 acc = {0.f, 0.f, 0.f, 0.f};
    #pragma unroll
    for (int kk = 0; kk < 8; ++kk)
      acc = __builtin_amdgcn_mfma_f32_16x16x32_bf16(a[kk], b[kk], acc, 0, 0, 0);

    const float ncol = lsqn[it * TCOLS + lcol];
    #pragma unroll
    for (int rg = 0; rg < 4; ++rg) {
      float sq = fmaxf(nrow[rg] + ncol - 2.0f * acc[rg], 0.0f);
      if (sq < m[rg][KNN - 1]) {
        float carry = sq;
        #pragma unroll
        for (int k = 0; k < KNN; ++k) {
          float mi = m[rg][k];
          m[rg][k] = fminf(mi, carry);
          carry    = fmaxf(mi, carry);
        }
      }
    }
    __syncthreads();  // drains own vmcnt (stage) + orders buf reuse
    buf ^= 1;
  }

  // Merge the 16 per-lane lists per row: 8x min-extraction via shfl_xor.
  const unsigned long long gmask = 0xFFFFULL << (lgrp * 16);
  #pragma unroll
  for (int rg = 0; rg < 4; ++rg) {
    const int row = wrow + lgrp * 4 + rg;
    #pragma unroll
    for (int t = 0; t < KNN; ++t) {
      float c  = m[rg][0];
      float mn = c;
      mn = fminf(mn, __shfl_xor(mn, 1));
      mn = fminf(mn, __shfl_xor(mn, 2));
      mn = fminf(mn, __shfl_xor(mn, 4));
      mn = fminf(mn, __shfl_xor(mn, 8));
      unsigned long long ball = __ballot(c == mn) & gmask;
      int owner = __ffsll((unsigned long long)ball) - 1;
      if (lane == owner) {
        #pragma unroll
        for (int k = 0; k < KNN - 1; ++k) m[rg][k] = m[rg][k + 1];
        m[rg][KNN - 1] = 1e30f;
      }
      if (lcol == t) knn_out[(row * jsplit + split) * KNN + t] = mn;
    }
  }
}

// Merge jsplit sorted-8 lists per row -> sum of global 8 smallest; reduce.
__global__ void k_final(const float* __restrict__ knn,
                        const float* __restrict__ sqn,
                        const float* __restrict__ colsum,
                        float* __restrict__ gacc, int jsplit) {
  const int tid = threadIdx.x;
  const int row = blockIdx.x * blockDim.x + tid;
  float m[KNN];
  #pragma unroll
  for (int i = 0; i < KNN; ++i) m[i] = 1e30f;
  const float* p = knn + row * (jsplit * KNN);
  for (int i = 0; i < jsplit * KNN; ++i) {
    float v = p[i];
    if (v < m[KNN - 1]) {
      float carry = v;
      #pragma unroll
      for (int k = 0; k < KNN; ++k) {
        float mi = m[k];
        m[k]  = fminf(mi, carry);
        carry = fmaxf(mi, carry);
      }
    }
  }
  float rs = 0.f;
  #pragma unroll
  for (int i = 0; i < KNN; ++i) rs += m[i];
  float s2 = sqn[row];

  __shared__ float red[2][4];
  #pragma unroll
  for (int off = 32; off > 0; off >>= 1) {
    rs += __shfl_down(rs, off);
    s2 += __shfl_down(s2, off);
  }
  if ((tid & 63) == 0) { red[0][tid >> 6] = rs; red[1][tid >> 6] = s2; }
  __syncthreads();
  if (tid == 0) {
    atomicAdd(&gacc[0], red[0][0] + red[0][1] + red[0][2] + red[0][3]);
    atomicAdd(&gacc[1], red[1][0] + red[1][1] + red[1][2] + red[1][3]);
  }
  if (blockIdx.x == 0) {
    float cs = colsum[tid];
    float q = cs * cs;
    #pragma unroll
    for (int off = 32; off > 0; off >>= 1) q += __shfl_down(q, off);
    __syncthreads();
    if ((tid & 63) == 0) red[0][tid >> 6] = q;
    __syncthreads();
    if (tid == 0) atomicAdd(&gacc[2], red[0][0] + red[0][1] + red[0][2] + red[0][3]);
  }
}

__global__ void k_out(const float* __restrict__ gacc, float* __restrict__ out) {
  if (threadIdx.x == 0 && blockIdx.x == 0) {
    float sum8 = gacc[0];
    float S2   = gacc[1];
    float Q    = gacc[2];
    float ref_var = (S2 - Q / (float)NROWS) / ((float)NDIM * (float)(NROWS - 1));
    out[0] = (sum8 / (float)(NROWS * KNN)) / ref_var;
  }
}

extern "C" void kernel_launch(void* const* d_in, const int* in_sizes, int n_in,
                              void* d_out, int out_size, void* d_ws, size_t ws_size,
                              hipStream_t stream) {
  const float* e = (const float*)d_in[0];
  char* ws = (char*)d_ws;
  ushort* ebf   = (ushort*)(ws + WS_EBF);
  float* sqn    = (float*)(ws + WS_SQN);
  float* colsum = (float*)(ws + WS_COL);
  float* gacc   = (float*)(ws + WS_ACC);
  float* knn    = (float*)(ws + WS_KNN);
  float* out    = (float*)d_out;

  const size_t need8 = (size_t)WS_KNN + (size_t)NROWS * 8 * KNN * 4;
  const int jsplit = (ws_size >= need8) ? 8 : 4;
  const int jrange = NROWS / jsplit;

  // zero atomic accumulators (colsum + gacc); harness doesn't re-poison ws.
  hipMemsetAsync(ws + WS_COL, 0, 2048, stream);

  hipLaunchKernelGGL(k_prep,   dim3(NROWS / 4), dim3(256), 0, stream, e, ebf, sqn);
  hipLaunchKernelGGL(k_colsum, dim3(32),        dim3(256), 0, stream, e, colsum);
  hipLaunchKernelGGL(k_main,   dim3(NROWS / 64, jsplit), dim3(256), 0, stream,
                     ebf, sqn, knn, jrange, jsplit);
  hipLaunchKernelGGL(k_final,  dim3(NROWS / 256), dim3(256), 0, stream,
                     knn, sqn, colsum, gacc, jsplit);
  hipLaunchKernelGGL(k_out,    dim3(1), dim3(1), 0, stream, gacc, out);
}

// Round 3
// 129.589 us; speedup vs baseline: 2.0591x; 1.0137x over previous
//
#include <hip/hip_runtime.h>
#include <hip/hip_bf16.h>

#define NROWS 8192
#define NDIM  256
#define KNN   8
#define TCOL  32                       // j-cols per LDS tile
#define TILE_B (TCOL * 512)            // 16 KiB per tile (32 cols x 512 B)
#define WAVES 4
#define ROWS_PER_WAVE 32
#define BLK_ROWS (WAVES * ROWS_PER_WAVE)  // 128 rows per block

typedef __attribute__((ext_vector_type(8)))  short bf16x8;
typedef __attribute__((ext_vector_type(16))) float f32x16;

// ---- workspace layout (bytes) ----
#define WS_EBF 0                        // 8192*256*2 = 4 MiB
#define WS_SQN (4*1024*1024)            // 32 KiB
#define WS_COL (WS_SQN + 32*1024)       // 1 KiB (colsum)
#define WS_ACC (WS_COL + 1024)          // 1 KiB (gacc: sum8, S2, Q)
#define WS_KNN (WS_ACC + 1024)          // NROWS*jsplit*KNN*4

// Convert e -> bf16 and compute per-row squared norms (fp32, exact).
__global__ void k_prep(const float* __restrict__ e,
                       ushort* __restrict__ ebf,
                       float* __restrict__ sqn) {
  const int lane = threadIdx.x & 63;
  const int row  = blockIdx.x * (blockDim.x >> 6) + (threadIdx.x >> 6);
  const float4 v = *reinterpret_cast<const float4*>(e + row * NDIM + lane * 4);
  ushort4 o;
  {
    __hip_bfloat16 b0 = __float2bfloat16(v.x);
    __hip_bfloat16 b1 = __float2bfloat16(v.y);
    __hip_bfloat16 b2 = __float2bfloat16(v.z);
    __hip_bfloat16 b3 = __float2bfloat16(v.w);
    o.x = *reinterpret_cast<ushort*>(&b0);
    o.y = *reinterpret_cast<ushort*>(&b1);
    o.z = *reinterpret_cast<ushort*>(&b2);
    o.w = *reinterpret_cast<ushort*>(&b3);
  }
  *reinterpret_cast<ushort4*>(ebf + row * NDIM + lane * 4) = o;
  float acc = v.x*v.x + v.y*v.y + v.z*v.z + v.w*v.w;
  #pragma unroll
  for (int off = 32; off > 0; off >>= 1) acc += __shfl_down(acc, off);
  if (lane == 0) sqn[row] = acc;
}

// Column sums (for ref_std). 256 blocks x 32 rows each, one atomic per dim.
__global__ void k_colsum(const float* __restrict__ e, float* __restrict__ colsum) {
  const int d  = threadIdx.x;
  const int r0 = blockIdx.x * 32;
  float s = 0.f;
  #pragma unroll 4
  for (int r = 0; r < 32; ++r) s += e[(r0 + r) * NDIM + d];
  atomicAdd(&colsum[d], s);
}

// Fused Gram + top-8.
// Swapped-operand 32x32x16 MFMA: D = jfrag * ifrag -> lane owns ONE i-row
// (col = lane&31) and its 16 regs are 16 j-candidates -> single top-8 list.
// LDS tile is K-major [kk][hi][col][16B] ^ ((kk&7)<<4): ds_read_b128 of a
// j-fragment is a contiguous 1 KiB wave read (conflict-free); ds_writes are
// 2-way (free). Staging is reg-based (coalesced dwordx4, issued early).
__launch_bounds__(256, 3)
__global__ void k_main(const ushort* __restrict__ eb,
                       const float* __restrict__ sqn,
                       float* __restrict__ knn_out,
                       int jrange, int jsplit) {
  __shared__ ushort lbuf[2][TILE_B / 2];   // 2 x 16 KiB
  __shared__ float  lsqn[1024];            // jrange <= 1024

  const int tid  = threadIdx.x;
  const int lane = tid & 63;
  const int wv   = tid >> 6;
  const int col  = lane & 31;              // i-row slot / j-col slot in reads
  const int hi   = lane >> 5;              // k-half selector
  const int rowi = blockIdx.x * BLK_ROWS + wv * ROWS_PER_WAVE + col;
  const int split = blockIdx.y;
  const int jbase = split * jrange;

  // i-fragments (intrinsic B operand), 16 K-chunks of 16 dims.
  bf16x8 ifrag[16];
  #pragma unroll
  for (int kk = 0; kk < 16; ++kk)
    ifrag[kk] = *reinterpret_cast<const bf16x8*>(eb + rowi * NDIM + kk * 16 + hi * 8);

  const float ni = sqn[rowi];

  float m[KNN];
  #pragma unroll
  for (int i = 0; i < KNN; ++i) m[i] = 1e30f;

  for (int i = tid; i < jrange; i += 256) lsqn[i] = sqn[jbase + i];

  uint4 st[4];
  auto load_tile = [&](int jb) {
    #pragma unroll
    for (int s = 0; s < 4; ++s) {
      const int q = s * 256 + tid;
      const int c = q >> 5, kc = q & 31;        // col, 16B k-chunk
      st[s] = *reinterpret_cast<const uint4*>(eb + (jb + c) * NDIM + kc * 8);
    }
  };
  auto write_tile = [&](int buf) {
    #pragma unroll
    for (int s = 0; s < 4; ++s) {
      const int q = s * 256 + tid;
      const int c = q >> 5, kc = q & 31;
      const int kk = kc >> 1, h = kc & 1;
      const int byte = (kk * 1024 + h * 512 + c * 16) ^ ((kk & 7) << 4);
      *reinterpret_cast<uint4*>(reinterpret_cast<char*>(&lbuf[buf][0]) + byte) = st[s];
    }
  };

  load_tile(jbase);
  __syncthreads();                 // (covers lsqn ordering too)
  write_tile(0);
  __syncthreads();

  const int nT = jrange / TCOL;
  for (int it = 0; it < nT; ++it) {
    const int buf = it & 1;
    if (it + 1 < nT) load_tile(jbase + (it + 1) * TCOL);   // issue early (T14)

    f32x16 acc;
    #pragma unroll
    for (int i = 0; i < 16; ++i) acc[i] = 0.f;
    #pragma unroll
    for (int kk = 0; kk < 16; ++kk) {
      const int byte = (kk * 1024 + hi * 512 + col * 16) ^ ((kk & 7) << 4);
      bf16x8 jf = *reinterpret_cast<const bf16x8*>(
          reinterpret_cast<const char*>(&lbuf[buf][0]) + byte);
      acc = __builtin_amdgcn_mfma_f32_32x32x16_bf16(jf, ifrag[kk], acc, 0, 0, 0);
    }

    // selection on w = nj - 2*dot (monotone in sq = ni + w); med3 insert.
    const int jloc = it * TCOL;
    #pragma unroll
    for (int g = 0; g < 4; ++g) {
      const float4 nj = *reinterpret_cast<const float4*>(&lsqn[jloc + g * 8 + hi * 4]);
      const float njv[4] = {nj.x, nj.y, nj.z, nj.w};
      #pragma unroll
      for (int q = 0; q < 4; ++q) {
        const float c = fmaf(-2.0f, acc[g * 4 + q], njv[q]);
        m[7] = __builtin_amdgcn_fmed3f(m[6], m[7], c);
        m[6] = __builtin_amdgcn_fmed3f(m[5], m[6], c);
        m[5] = __builtin_amdgcn_fmed3f(m[4], m[5], c);
        m[4] = __builtin_amdgcn_fmed3f(m[3], m[4], c);
        m[3] = __builtin_amdgcn_fmed3f(m[2], m[3], c);
        m[2] = __builtin_amdgcn_fmed3f(m[1], m[2], c);
        m[1] = __builtin_amdgcn_fmed3f(m[0], m[1], c);
        m[0] = fminf(m[0], c);
      }
    }

    if (it + 1 < nT) {
      __syncthreads();             // everyone done reading buf^1 (last iter)
      write_tile(buf ^ 1);
      __syncthreads();             // new tile visible
    }
  }

  // Merge the two k-half lists for this row (lane <-> lane+32): the 8
  // smallest of two sorted-8 lists are elementwise min(a_k, b_{7-k}).
  float mg[KNN];
  #pragma unroll
  for (int k = 0; k < KNN; ++k) {
    const float p = __shfl_xor(m[KNN - 1 - k], 32);
    mg[k] = fminf(m[k], p);
  }
  if (hi == 0) {
    float* dst = knn_out + ((size_t)rowi * jsplit + split) * KNN;
    #pragma unroll
    for (int k = 0; k < KNN; ++k)
      dst[k] = fmaxf(ni + mg[k], 0.0f);     // clamped squared distance
  }
}

// Merge jsplit sorted-8 lists per row -> sum of global 8 smallest; reduce.
__global__ void k_final(const float* __restrict__ knn,
                        const float* __restrict__ sqn,
                        const float* __restrict__ colsum,
                        float* __restrict__ gacc, int jsplit) {
  const int tid = threadIdx.x;
  const int row = blockIdx.x * blockDim.x + tid;
  float m[KNN];
  #pragma unroll
  for (int i = 0; i < KNN; ++i) m[i] = 1e30f;
  const float* p = knn + (size_t)row * (jsplit * KNN);
  for (int i = 0; i < jsplit * KNN; ++i) {
    const float c = p[i];
    m[7] = __builtin_amdgcn_fmed3f(m[6], m[7], c);
    m[6] = __builtin_amdgcn_fmed3f(m[5], m[6], c);
    m[5] = __builtin_amdgcn_fmed3f(m[4], m[5], c);
    m[4] = __builtin_amdgcn_fmed3f(m[3], m[4], c);
    m[3] = __builtin_amdgcn_fmed3f(m[2], m[3], c);
    m[2] = __builtin_amdgcn_fmed3f(m[1], m[2], c);
    m[1] = __builtin_amdgcn_fmed3f(m[0], m[1], c);
    m[0] = fminf(m[0], c);
  }
  float rs = 0.f;
  #pragma unroll
  for (int i = 0; i < KNN; ++i) rs += m[i];
  float s2 = sqn[row];

  __shared__ float red[2][4];
  #pragma unroll
  for (int off = 32; off > 0; off >>= 1) {
    rs += __shfl_down(rs, off);
    s2 += __shfl_down(s2, off);
  }
  if ((tid & 63) == 0) { red[0][tid >> 6] = rs; red[1][tid >> 6] = s2; }
  __syncthreads();
  if (tid == 0) {
    atomicAdd(&gacc[0], red[0][0] + red[0][1] + red[0][2] + red[0][3]);
    atomicAdd(&gacc[1], red[1][0] + red[1][1] + red[1][2] + red[1][3]);
  }
  if (blockIdx.x == 0) {
    const float cs = colsum[tid];
    float q = cs * cs;
    #pragma unroll
    for (int off = 32; off > 0; off >>= 1) q += __shfl_down(q, off);
    __syncthreads();
    if ((tid & 63) == 0) red[0][tid >> 6] = q;
    __syncthreads();
    if (tid == 0) atomicAdd(&gacc[2], red[0][0] + red[0][1] + red[0][2] + red[0][3]);
  }
}

__global__ void k_out(const float* __restrict__ gacc, float* __restrict__ out) {
  if (threadIdx.x == 0 && blockIdx.x == 0) {
    const float sum8 = gacc[0];
    const float S2   = gacc[1];
    const float Q    = gacc[2];
    const float ref_var = (S2 - Q / (float)NROWS) / ((float)NDIM * (float)(NROWS - 1));
    out[0] = (sum8 / (float)(NROWS * KNN)) / ref_var;
  }
}

extern "C" void kernel_launch(void* const* d_in, const int* in_sizes, int n_in,
                              void* d_out, int out_size, void* d_ws, size_t ws_size,
                              hipStream_t stream) {
  const float* e = (const float*)d_in[0];
  char* ws = (char*)d_ws;
  ushort* ebf   = (ushort*)(ws + WS_EBF);
  float* sqn    = (float*)(ws + WS_SQN);
  float* colsum = (float*)(ws + WS_COL);
  float* gacc   = (float*)(ws + WS_ACC);
  float* knn    = (float*)(ws + WS_KNN);
  float* out    = (float*)d_out;

  const size_t need16 = (size_t)WS_KNN + (size_t)NROWS * 16 * KNN * 4;
  const int jsplit = (ws_size >= need16) ? 16 : 8;
  const int jrange = NROWS / jsplit;

  // zero atomic accumulators (colsum + gacc); harness doesn't re-poison ws.
  hipMemsetAsync(ws + WS_COL, 0, 2048, stream);

  hipLaunchKernelGGL(k_prep,   dim3(NROWS / 4), dim3(256), 0, stream, e, ebf, sqn);
  hipLaunchKernelGGL(k_colsum, dim3(256),       dim3(256), 0, stream, e, colsum);
  hipLaunchKernelGGL(k_main,   dim3(NROWS / BLK_ROWS, jsplit), dim3(256), 0, stream,
                     ebf, sqn, knn, jrange, jsplit);
  hipLaunchKernelGGL(k_final,  dim3(NROWS / 256), dim3(256), 0, stream,
                     knn, sqn, colsum, gacc, jsplit);
  hipLaunchKernelGGL(k_out,    dim3(1), dim3(1), 0, stream, gacc, out);
}

// Round 4
// 103.966 us; speedup vs baseline: 2.5666x; 1.2465x over previous
//
#include <hip/hip_runtime.h>
#include <hip/hip_bf16.h>

#define NROWS 8192
#define NDIM  256
#define KNN   8
#define TCOL  32                          // j-cols per LDS tile (16 KiB)
#define BLK_ROWS 128                      // 4 waves x 32 rows

typedef __attribute__((ext_vector_type(8)))  short bf16x8;
typedef __attribute__((ext_vector_type(16))) float f32x16;

// ---- workspace layout (bytes) ----
#define WS_EBF 0                          // 8192*256*2 = 4 MiB
#define WS_SQN (4*1024*1024)              // 32 KiB
#define WS_COL (WS_SQN + 32*1024)         // 1 KiB (colsum)
#define WS_ACC (WS_COL + 1024)            // 1 KiB (gacc)
#define WS_KNN (WS_ACC + 1024)            // [jsplit][NROWS][KNN] f32

// e -> bf16, per-row squared norms, AND column sums (one pass over e).
// 256 blocks x 32 rows; wave w handles rows wv*8..wv*8+7 of the block.
__global__ void k_prep(const float* __restrict__ e,
                       ushort* __restrict__ ebf,
                       float* __restrict__ sqn,
                       float* __restrict__ colsum) {
  __shared__ float lcs[NDIM];
  const int tid  = threadIdx.x;
  const int lane = tid & 63;
  const int wv   = tid >> 6;
  lcs[tid] = 0.f;
  __syncthreads();
  float4 cs = {0.f, 0.f, 0.f, 0.f};
  #pragma unroll
  for (int r = 0; r < 8; ++r) {
    const int row = blockIdx.x * 32 + wv * 8 + r;
    const float4 v = *reinterpret_cast<const float4*>(e + (size_t)row * NDIM + lane * 4);
    ushort4 o;
    __hip_bfloat16 b0 = __float2bfloat16(v.x), b1 = __float2bfloat16(v.y);
    __hip_bfloat16 b2 = __float2bfloat16(v.z), b3 = __float2bfloat16(v.w);
    o.x = *reinterpret_cast<ushort*>(&b0); o.y = *reinterpret_cast<ushort*>(&b1);
    o.z = *reinterpret_cast<ushort*>(&b2); o.w = *reinterpret_cast<ushort*>(&b3);
    *reinterpret_cast<ushort4*>(ebf + (size_t)row * NDIM + lane * 4) = o;
    float acc = v.x*v.x + v.y*v.y + v.z*v.z + v.w*v.w;
    #pragma unroll
    for (int off = 32; off > 0; off >>= 1) acc += __shfl_down(acc, off);
    if (lane == 0) sqn[row] = acc;
    cs.x += v.x; cs.y += v.y; cs.z += v.z; cs.w += v.w;
  }
  atomicAdd(&lcs[lane * 4 + 0], cs.x);
  atomicAdd(&lcs[lane * 4 + 1], cs.y);
  atomicAdd(&lcs[lane * 4 + 2], cs.z);
  atomicAdd(&lcs[lane * 4 + 3], cs.w);
  __syncthreads();
  atomicAdd(&colsum[tid], lcs[tid]);
}

// Fused Gram + top-8.
// Swapped 32x32x16 MFMA (D = jf * if): lane owns one i-row (col=lane&31);
// 16 acc regs = 16 j-candidates -> one top-8 list per lane.
// LDS: K-major [kk][hi][col][16B] ^ ((kk&7)<<4); staged by global_load_lds
// with linear dest + inverse-swizzled per-lane SOURCE (rule 21 / m173).
// One barrier per iter (stage of buf^1 only races reads that finished
// before the previous barrier). Two independent MFMA chains (depth 8) and
// selection deferred one iteration (w_prev) so med3 VALU fills MFMA latency.
__launch_bounds__(256, 3)
__global__ void k_main(const ushort* __restrict__ eb,
                       const float* __restrict__ sqn,
                       float* __restrict__ knn_out,
                       int jrange, int jsplit) {
  __shared__ ushort lbuf[2][TCOL * NDIM];   // 2 x 16 KiB
  __shared__ float  lsqn[512];              // jrange <= 512

  const int tid  = threadIdx.x;
  const int lane = tid & 63;
  const int wv   = tid >> 6;
  const int col  = lane & 31;
  const int hi   = lane >> 5;
  const int rowi = blockIdx.x * BLK_ROWS + wv * 32 + col;
  const int split = blockIdx.y;
  const int jbase = split * jrange;

  // i-fragments: 16 K-chunks of 16 dims (lane's full row cached via L1).
  bf16x8 ifrag[16];
  #pragma unroll
  for (int kk = 0; kk < 16; ++kk)
    ifrag[kk] = *reinterpret_cast<const bf16x8*>(eb + (size_t)rowi * NDIM + kk * 16 + hi * 8);
  const float ni = sqn[rowi];

  float m[KNN];
  #pragma unroll
  for (int i = 0; i < KNN; ++i) m[i] = 1e30f;

  for (int i = tid; i < jrange; i += 256) lsqn[i] = sqn[jbase + i];

  auto stage = [&](int bufi, int jb) {
    #pragma unroll
    for (int s = 0; s < 4; ++s) {
      const int o  = s * 4096 + wv * 1024 + lane * 16;   // linear LDS byte
      const int kk = o >> 10;
      const int h  = (o >> 9) & 1;
      const int c  = ((o & 511) ^ ((kk & 7) << 4)) >> 4; // inverse swizzle on SOURCE
      const ushort* src = eb + (size_t)(jb + c) * NDIM + (kk * 2 + h) * 8;
      __builtin_amdgcn_global_load_lds(
          (const __attribute__((address_space(1))) void*)src,
          (__attribute__((address_space(3))) void*)(
              reinterpret_cast<char*>(&lbuf[bufi][0]) + s * 4096 + wv * 1024),
          16, 0, 0);
    }
  };

  float w[16];
  #pragma unroll
  for (int q = 0; q < 16; ++q) w[q] = 1e30f;   // first-iter selection is a no-op

  stage(0, jbase);
  asm volatile("s_waitcnt vmcnt(0)" ::: "memory");
  __syncthreads();

  const int nT = jrange / TCOL;
  int buf = 0;
  for (int it = 0; it < nT; ++it) {
    if (it + 1 < nT) stage(buf ^ 1, jbase + (it + 1) * TCOL);

    // nj for THIS tile (consumed at the w-update below).
    float njv[16];
    #pragma unroll
    for (int g = 0; g < 4; ++g) {
      const float4 t = *reinterpret_cast<const float4*>(&lsqn[it * TCOL + g * 8 + hi * 4]);
      njv[g*4+0] = t.x; njv[g*4+1] = t.y; njv[g*4+2] = t.z; njv[g*4+3] = t.w;
    }

    // two independent MFMA chains over K (depth 8 each)
    f32x16 acc0, acc1;
    #pragma unroll
    for (int i = 0; i < 16; ++i) { acc0[i] = 0.f; acc1[i] = 0.f; }
    #pragma unroll
    for (int kk = 0; kk < 8; ++kk) {
      const int b0 = (kk * 1024 + hi * 512 + col * 16) ^ ((kk & 7) << 4);
      const int b1 = ((kk + 8) * 1024 + hi * 512 + col * 16) ^ ((kk & 7) << 4);
      const bf16x8 jf0 = *reinterpret_cast<const bf16x8*>(
          reinterpret_cast<const char*>(&lbuf[buf][0]) + b0);
      const bf16x8 jf1 = *reinterpret_cast<const bf16x8*>(
          reinterpret_cast<const char*>(&lbuf[buf][0]) + b1);
      acc0 = __builtin_amdgcn_mfma_f32_32x32x16_bf16(jf0, ifrag[kk],     acc0, 0, 0, 0);
      acc1 = __builtin_amdgcn_mfma_f32_32x32x16_bf16(jf1, ifrag[kk + 8], acc1, 0, 0, 0);
    }

    // selection on PREVIOUS tile's w (independent of this tile's MFMAs —
    // scheduler interleaves it into the MFMA latency shadow).
    #pragma unroll
    for (int q = 0; q < 16; ++q) {
      const float c = w[q];
      m[7] = __builtin_amdgcn_fmed3f(m[6], m[7], c);
      m[6] = __builtin_amdgcn_fmed3f(m[5], m[6], c);
      m[5] = __builtin_amdgcn_fmed3f(m[4], m[5], c);
      m[4] = __builtin_amdgcn_fmed3f(m[3], m[4], c);
      m[3] = __builtin_amdgcn_fmed3f(m[2], m[2+1], c);
      m[2] = __builtin_amdgcn_fmed3f(m[1], m[2], c);
      m[1] = __builtin_amdgcn_fmed3f(m[0], m[1], c);
      m[0] = fminf(m[0], c);
    }

    // w for this tile: w = nj - 2*(acc0+acc1)  (monotone key; +ni deferred)
    #pragma unroll
    for (int q = 0; q < 16; ++q)
      w[q] = fmaf(-2.0f, acc0[q] + acc1[q], njv[q]);

    asm volatile("s_waitcnt vmcnt(0)" ::: "memory");
    __syncthreads();
    buf ^= 1;
  }

  // final deferred selection
  #pragma unroll
  for (int q = 0; q < 16; ++q) {
    const float c = w[q];
    m[7] = __builtin_amdgcn_fmed3f(m[6], m[7], c);
    m[6] = __builtin_amdgcn_fmed3f(m[5], m[6], c);
    m[5] = __builtin_amdgcn_fmed3f(m[4], m[5], c);
    m[4] = __builtin_amdgcn_fmed3f(m[3], m[4], c);
    m[3] = __builtin_amdgcn_fmed3f(m[2], m[3], c);
    m[2] = __builtin_amdgcn_fmed3f(m[1], m[2], c);
    m[1] = __builtin_amdgcn_fmed3f(m[0], m[1], c);
    m[0] = fminf(m[0], c);
  }

  // merge k-half lists (lane <-> lane+32): mins of two sorted-8 lists are
  // elementwise min(a_k, b_{7-k}).
  float mg[KNN];
  #pragma unroll
  for (int k = 0; k < KNN; ++k) {
    const float p = __shfl_xor(m[KNN - 1 - k], 32);
    mg[k] = fminf(m[k], p);
  }
  if (hi == 0) {
    float* dst = knn_out + ((size_t)split * NROWS + rowi) * KNN;
    #pragma unroll
    for (int k = 0; k < KNN; ++k)
      dst[k] = fmaxf(ni + mg[k], 0.0f);
  }
}

// Merge jsplit sorted-8 lists per row ([split][row][8] layout, coalesced),
// then global reductions.
__global__ void k_final(const float* __restrict__ knn,
                        const float* __restrict__ sqn,
                        const float* __restrict__ colsum,
                        float* __restrict__ gacc, int jsplit) {
  const int tid = threadIdx.x;
  const int row = blockIdx.x * blockDim.x + tid;
  float m[KNN];
  #pragma unroll
  for (int i = 0; i < KNN; ++i) m[i] = 1e30f;
  for (int s = 0; s < jsplit; ++s) {
    const float* p = knn + ((size_t)s * NROWS + row) * KNN;
    #pragma unroll
    for (int i = 0; i < KNN; ++i) {
      const float c = p[i];
      m[7] = __builtin_amdgcn_fmed3f(m[6], m[7], c);
      m[6] = __builtin_amdgcn_fmed3f(m[5], m[6], c);
      m[5] = __builtin_amdgcn_fmed3f(m[4], m[5], c);
      m[4] = __builtin_amdgcn_fmed3f(m[3], m[4], c);
      m[3] = __builtin_amdgcn_fmed3f(m[2], m[3], c);
      m[2] = __builtin_amdgcn_fmed3f(m[1], m[2], c);
      m[1] = __builtin_amdgcn_fmed3f(m[0], m[1], c);
      m[0] = fminf(m[0], c);
    }
  }
  float rs = 0.f;
  #pragma unroll
  for (int i = 0; i < KNN; ++i) rs += m[i];
  float s2 = sqn[row];

  __shared__ float red[2][4];
  #pragma unroll
  for (int off = 32; off > 0; off >>= 1) {
    rs += __shfl_down(rs, off);
    s2 += __shfl_down(s2, off);
  }
  if ((tid & 63) == 0) { red[0][tid >> 6] = rs; red[1][tid >> 6] = s2; }
  __syncthreads();
  if (tid == 0) {
    atomicAdd(&gacc[0], red[0][0] + red[0][1] + red[0][2] + red[0][3]);
    atomicAdd(&gacc[1], red[1][0] + red[1][1] + red[1][2] + red[1][3]);
  }
  if (blockIdx.x == 0) {
    const float cs = colsum[tid];
    float q = cs * cs;
    #pragma unroll
    for (int off = 32; off > 0; off >>= 1) q += __shfl_down(q, off);
    __syncthreads();
    if ((tid & 63) == 0) red[0][tid >> 6] = q;
    __syncthreads();
    if (tid == 0) atomicAdd(&gacc[2], red[0][0] + red[0][1] + red[0][2] + red[0][3]);
  }
}

__global__ void k_out(const float* __restrict__ gacc, float* __restrict__ out) {
  if (threadIdx.x == 0 && blockIdx.x == 0) {
    const float sum8 = gacc[0];
    const float S2   = gacc[1];
    const float Q    = gacc[2];
    const float ref_var = (S2 - Q / (float)NROWS) / ((float)NDIM * (float)(NROWS - 1));
    out[0] = (sum8 / (float)(NROWS * KNN)) / ref_var;
  }
}

extern "C" void kernel_launch(void* const* d_in, const int* in_sizes, int n_in,
                              void* d_out, int out_size, void* d_ws, size_t ws_size,
                              hipStream_t stream) {
  const float* e = (const float*)d_in[0];
  char* ws = (char*)d_ws;
  ushort* ebf   = (ushort*)(ws + WS_EBF);
  float* sqn    = (float*)(ws + WS_SQN);
  float* colsum = (float*)(ws + WS_COL);
  float* gacc   = (float*)(ws + WS_ACC);
  float* knn    = (float*)(ws + WS_KNN);
  float* out    = (float*)d_out;

  const size_t need32 = (size_t)WS_KNN + (size_t)NROWS * 32 * KNN * 4;
  const int jsplit = (ws_size >= need32) ? 32 : 16;
  const int jrange = NROWS / jsplit;

  // zero atomic accumulators (colsum + gacc); harness doesn't re-poison ws.
  hipMemsetAsync(ws + WS_COL, 0, 2048, stream);

  hipLaunchKernelGGL(k_prep,  dim3(NROWS / 32), dim3(256), 0, stream, e, ebf, sqn, colsum);
  hipLaunchKernelGGL(k_main,  dim3(NROWS / BLK_ROWS, jsplit), dim3(256), 0, stream,
                     ebf, sqn, knn, jrange, jsplit);
  hipLaunchKernelGGL(k_final, dim3(NROWS / 256), dim3(256), 0, stream,
                     knn, sqn, colsum, gacc, jsplit);
  hipLaunchKernelGGL(k_out,   dim3(1), dim3(1), 0, stream, gacc, out);
}

// Round 5
// 87.596 us; speedup vs baseline: 3.0462x; 1.1869x over previous
//
#include <hip/hip_runtime.h>
#include <hip/hip_bf16.h>

#define NROWS 8192
#define NDIM  256
#define KNN   8
#define TCOL  32                          // j-cols per LDS tile (16 KiB)
#define BLK_ROWS 128                      // 4 waves x 32 rows

typedef __attribute__((ext_vector_type(8)))  short bf16x8;
typedef __attribute__((ext_vector_type(16))) float f32x16;

// ---- workspace layout (bytes) ----
#define WS_EBF 0                          // 8192*256*2 = 4 MiB
#define WS_SQN (4*1024*1024)              // 32 KiB
#define WS_COL (WS_SQN + 32*1024)         // 1 KiB (colsum)
#define WS_ACC (WS_COL + 1024)            // 1 KiB (gacc + counter)
#define WS_KNN (WS_ACC + 1024)            // [jsplit][NROWS][KNN] f32

// e -> bf16, per-row squared norms, AND column sums (one pass over e).
__global__ void k_prep(const float* __restrict__ e,
                       ushort* __restrict__ ebf,
                       float* __restrict__ sqn,
                       float* __restrict__ colsum) {
  __shared__ float lcs[NDIM];
  const int tid  = threadIdx.x;
  const int lane = tid & 63;
  const int wv   = tid >> 6;
  lcs[tid] = 0.f;
  __syncthreads();
  float4 cs = {0.f, 0.f, 0.f, 0.f};
  #pragma unroll
  for (int r = 0; r < 8; ++r) {
    const int row = blockIdx.x * 32 + wv * 8 + r;
    const float4 v = *reinterpret_cast<const float4*>(e + (size_t)row * NDIM + lane * 4);
    ushort4 o;
    __hip_bfloat16 b0 = __float2bfloat16(v.x), b1 = __float2bfloat16(v.y);
    __hip_bfloat16 b2 = __float2bfloat16(v.z), b3 = __float2bfloat16(v.w);
    o.x = *reinterpret_cast<ushort*>(&b0); o.y = *reinterpret_cast<ushort*>(&b1);
    o.z = *reinterpret_cast<ushort*>(&b2); o.w = *reinterpret_cast<ushort*>(&b3);
    *reinterpret_cast<ushort4*>(ebf + (size_t)row * NDIM + lane * 4) = o;
    float acc = v.x*v.x + v.y*v.y + v.z*v.z + v.w*v.w;
    #pragma unroll
    for (int off = 32; off > 0; off >>= 1) acc += __shfl_down(acc, off);
    if (lane == 0) sqn[row] = acc;
    cs.x += v.x; cs.y += v.y; cs.z += v.z; cs.w += v.w;
  }
  atomicAdd(&lcs[lane * 4 + 0], cs.x);
  atomicAdd(&lcs[lane * 4 + 1], cs.y);
  atomicAdd(&lcs[lane * 4 + 2], cs.z);
  atomicAdd(&lcs[lane * 4 + 3], cs.w);
  __syncthreads();
  atomicAdd(&colsum[tid], lcs[tid]);
}

// Fused Gram + top-8.
// Swapped 32x32x16 MFMA (D = jf * if): lane owns one i-row (col=lane&31);
// 16 acc regs = 16 j-candidates -> one top-8 list per lane.
// LDS: K-major [kk][hi][col][16B] ^ ((kk&7)<<4); staged by global_load_lds
// with linear dest + inverse-swizzled per-lane SOURCE. One barrier/iter.
// Register budget: single 16-deep MFMA chain, selection immediately after
// (acc dies in place) -> ~105 live VGPRs, pure-VGPR at 4 waves/SIMD.
__launch_bounds__(256, 4)
__global__ void k_main(const ushort* __restrict__ eb,
                       const float* __restrict__ sqn,
                       float* __restrict__ knn_out,
                       int jrange, int jsplit) {
  __shared__ ushort lbuf[2][TCOL * NDIM];   // 2 x 16 KiB
  __shared__ float  lsqn[1024];             // jrange <= 1024

  const int tid  = threadIdx.x;
  const int lane = tid & 63;
  const int wv   = tid >> 6;
  const int col  = lane & 31;
  const int hi   = lane >> 5;
  const int rowi = blockIdx.x * BLK_ROWS + wv * 32 + col;
  const int split = blockIdx.y;
  const int jbase = split * jrange;

  // i-fragments: lane's full row, 16 K-chunks of 16 dims (64 VGPRs).
  bf16x8 ifrag[16];
  #pragma unroll
  for (int kk = 0; kk < 16; ++kk)
    ifrag[kk] = *reinterpret_cast<const bf16x8*>(eb + (size_t)rowi * NDIM + kk * 16 + hi * 8);
  const float ni = sqn[rowi];

  float m[KNN];
  #pragma unroll
  for (int i = 0; i < KNN; ++i) m[i] = 1e30f;

  for (int i = tid; i < jrange; i += 256) lsqn[i] = sqn[jbase + i];

  auto stage = [&](int bufi, int jb) {
    #pragma unroll
    for (int s = 0; s < 4; ++s) {
      const int o  = s * 4096 + wv * 1024 + lane * 16;   // linear LDS byte
      const int kk = o >> 10;
      const int h  = (o >> 9) & 1;
      const int c  = ((o & 511) ^ ((kk & 7) << 4)) >> 4; // inverse swizzle on SOURCE
      const ushort* src = eb + (size_t)(jb + c) * NDIM + (kk * 2 + h) * 8;
      __builtin_amdgcn_global_load_lds(
          (const __attribute__((address_space(1))) void*)src,
          (__attribute__((address_space(3))) void*)(
              reinterpret_cast<char*>(&lbuf[bufi][0]) + s * 4096 + wv * 1024),
          16, 0, 0);
    }
  };

  stage(0, jbase);
  asm volatile("s_waitcnt vmcnt(0)" ::: "memory");
  __syncthreads();

  const int nT = jrange / TCOL;
  int buf = 0;
  for (int it = 0; it < nT; ++it) {
    if (it + 1 < nT) stage(buf ^ 1, jbase + (it + 1) * TCOL);

    // single 16-deep MFMA chain; TLP (16 waves/CU) hides the dep latency.
    f32x16 acc;
    #pragma unroll
    for (int i = 0; i < 16; ++i) acc[i] = 0.f;
    #pragma unroll
    for (int kk = 0; kk < 16; ++kk) {
      const int b0 = (kk * 1024 + hi * 512 + col * 16) ^ ((kk & 7) << 4);
      const bf16x8 jf = *reinterpret_cast<const bf16x8*>(
          reinterpret_cast<const char*>(&lbuf[buf][0]) + b0);
      acc = __builtin_amdgcn_mfma_f32_32x32x16_bf16(jf, ifrag[kk], acc, 0, 0, 0);
    }

    // selection on w = nj - 2*dot (monotone in sq = ni + w); acc dies here.
    #pragma unroll
    for (int g = 0; g < 4; ++g) {
      const float4 nj = *reinterpret_cast<const float4*>(&lsqn[it * TCOL + g * 8 + hi * 4]);
      const float njv[4] = {nj.x, nj.y, nj.z, nj.w};
      #pragma unroll
      for (int q = 0; q < 4; ++q) {
        const float c = fmaf(-2.0f, acc[g * 4 + q], njv[q]);
        m[7] = __builtin_amdgcn_fmed3f(m[6], m[7], c);
        m[6] = __builtin_amdgcn_fmed3f(m[5], m[6], c);
        m[5] = __builtin_amdgcn_fmed3f(m[4], m[5], c);
        m[4] = __builtin_amdgcn_fmed3f(m[3], m[4], c);
        m[3] = __builtin_amdgcn_fmed3f(m[2], m[3], c);
        m[2] = __builtin_amdgcn_fmed3f(m[1], m[2], c);
        m[1] = __builtin_amdgcn_fmed3f(m[0], m[1], c);
        m[0] = fminf(m[0], c);
      }
    }

    asm volatile("s_waitcnt vmcnt(0)" ::: "memory");
    __syncthreads();
    buf ^= 1;
  }

  // merge k-half lists (lane <-> lane+32): mins of two sorted-8 lists are
  // elementwise min(a_k, b_{7-k}).
  float mg[KNN];
  #pragma unroll
  for (int k = 0; k < KNN; ++k) {
    const float p = __shfl_xor(m[KNN - 1 - k], 32);
    mg[k] = fminf(m[k], p);
  }
  if (hi == 0) {
    float* dst = knn_out + ((size_t)split * NROWS + rowi) * KNN;
    #pragma unroll
    for (int k = 0; k < KNN; ++k)
      dst[k] = fmaxf(ni + mg[k], 0.0f);
  }
}

// Merge jsplit 8-sets per row ([split][row][8] layout, coalesced), global
// reductions, and (last finishing block) the final scalar — fused k_out.
__global__ void k_final(const float* __restrict__ knn,
                        const float* __restrict__ sqn,
                        const float* __restrict__ colsum,
                        float* __restrict__ gacc,
                        float* __restrict__ out, int jsplit) {
  const int tid = threadIdx.x;
  const int row = blockIdx.x * blockDim.x + tid;
  float m[KNN];
  #pragma unroll
  for (int i = 0; i < KNN; ++i) m[i] = 1e30f;
  for (int s = 0; s < jsplit; ++s) {
    const float* p = knn + ((size_t)s * NROWS + row) * KNN;
    #pragma unroll
    for (int i = 0; i < KNN; ++i) {
      const float c = p[i];
      m[7] = __builtin_amdgcn_fmed3f(m[6], m[7], c);
      m[6] = __builtin_amdgcn_fmed3f(m[5], m[6], c);
      m[5] = __builtin_amdgcn_fmed3f(m[4], m[5], c);
      m[4] = __builtin_amdgcn_fmed3f(m[3], m[4], c);
      m[3] = __builtin_amdgcn_fmed3f(m[2], m[3], c);
      m[2] = __builtin_amdgcn_fmed3f(m[1], m[2], c);
      m[1] = __builtin_amdgcn_fmed3f(m[0], m[1], c);
      m[0] = fminf(m[0], c);
    }
  }
  float rs = 0.f;
  #pragma unroll
  for (int i = 0; i < KNN; ++i) rs += m[i];
  float s2 = sqn[row];

  __shared__ float red[2][4];
  #pragma unroll
  for (int off = 32; off > 0; off >>= 1) {
    rs += __shfl_down(rs, off);
    s2 += __shfl_down(s2, off);
  }
  if ((tid & 63) == 0) { red[0][tid >> 6] = rs; red[1][tid >> 6] = s2; }
  __syncthreads();
  if (tid == 0) {
    atomicAdd(&gacc[0], red[0][0] + red[0][1] + red[0][2] + red[0][3]);
    atomicAdd(&gacc[1], red[1][0] + red[1][1] + red[1][2] + red[1][3]);
  }
  if (blockIdx.x == 0) {
    const float cs = colsum[tid];
    float q = cs * cs;
    #pragma unroll
    for (int off = 32; off > 0; off >>= 1) q += __shfl_down(q, off);
    __syncthreads();
    if ((tid & 63) == 0) red[0][tid >> 6] = q;
    __syncthreads();
    if (tid == 0) atomicAdd(&gacc[2], red[0][0] + red[0][1] + red[0][2] + red[0][3]);
  }
  // completion: last block to finish computes the output scalar.
  if (tid == 0) {
    __threadfence();
    int* cnt = (int*)(gacc + 3);
    const int prev = atomicAdd(cnt, 1);
    if (prev == (int)gridDim.x - 1) {
      const float sum8 = atomicAdd(&gacc[0], 0.0f);
      const float S2   = atomicAdd(&gacc[1], 0.0f);
      const float Q    = atomicAdd(&gacc[2], 0.0f);
      const float ref_var = (S2 - Q / (float)NROWS) / ((float)NDIM * (float)(NROWS - 1));
      out[0] = (sum8 / (float)(NROWS * KNN)) / ref_var;
    }
  }
}

extern "C" void kernel_launch(void* const* d_in, const int* in_sizes, int n_in,
                              void* d_out, int out_size, void* d_ws, size_t ws_size,
                              hipStream_t stream) {
  const float* e = (const float*)d_in[0];
  char* ws = (char*)d_ws;
  ushort* ebf   = (ushort*)(ws + WS_EBF);
  float* sqn    = (float*)(ws + WS_SQN);
  float* colsum = (float*)(ws + WS_COL);
  float* gacc   = (float*)(ws + WS_ACC);
  float* knn    = (float*)(ws + WS_KNN);
  float* out    = (float*)d_out;

  const size_t need16 = (size_t)WS_KNN + (size_t)NROWS * 16 * KNN * 4;
  const int jsplit = (ws_size >= need16) ? 16 : 8;
  const int jrange = NROWS / jsplit;

  // zero atomic accumulators (colsum + gacc + counter); harness doesn't
  // re-poison ws between timed replays.
  hipMemsetAsync(ws + WS_COL, 0, 2048, stream);

  hipLaunchKernelGGL(k_prep,  dim3(NROWS / 32), dim3(256), 0, stream, e, ebf, sqn, colsum);
  hipLaunchKernelGGL(k_main,  dim3(NROWS / BLK_ROWS, jsplit), dim3(256), 0, stream,
                     ebf, sqn, knn, jrange, jsplit);
  hipLaunchKernelGGL(k_final, dim3(NROWS / 256), dim3(256), 0, stream,
                     knn, sqn, colsum, gacc, out, jsplit);
}

// Round 6
// 81.418 us; speedup vs baseline: 3.2774x; 1.0759x over previous
//
#include <hip/hip_runtime.h>
#include <hip/hip_bf16.h>

#define NROWS 8192
#define NDIM  256
#define KNN   8
#define TCOL  32                          // j-cols per LDS tile (16 KiB)
#define BLK_ROWS 256                      // 4 waves x 64 rows (R=2)

typedef __attribute__((ext_vector_type(8)))  short bf16x8;
typedef __attribute__((ext_vector_type(16))) float f32x16;

// ---- workspace layout (bytes) ----
#define WS_EBF 0                          // 8192*256*2 = 4 MiB
#define WS_SQN (4*1024*1024)              // 32 KiB
#define WS_PCS (WS_SQN + 32*1024)         // 128 blocks x 256 f32 = 128 KiB
#define WS_ACC (WS_PCS + 128*1024)        // 1 KiB (gacc[0..2] + counter)
#define WS_KNN (WS_ACC + 1024)            // [jsplit][NROWS][KNN] f32

// e -> bf16, per-row squared norms, per-block column-sum partials.
// 128 blocks x 64 rows; wave wv handles 16 rows. Block 0 zeroes gacc+counter
// (safe: only k_final — a later kernel — reads them).
__global__ void k_prep(const float* __restrict__ e,
                       ushort* __restrict__ ebf,
                       float* __restrict__ sqn,
                       float* __restrict__ pcs,
                       float* __restrict__ gacc) {
  __shared__ float lcs[NDIM];
  const int tid  = threadIdx.x;
  const int lane = tid & 63;
  const int wv   = tid >> 6;
  if (blockIdx.x == 0 && tid < 8) ((int*)gacc)[tid] = 0;
  lcs[tid] = 0.f;
  __syncthreads();
  float4 cs = {0.f, 0.f, 0.f, 0.f};
  #pragma unroll
  for (int r = 0; r < 16; ++r) {
    const int row = blockIdx.x * 64 + wv * 16 + r;
    const float4 v = *reinterpret_cast<const float4*>(e + (size_t)row * NDIM + lane * 4);
    ushort4 o;
    __hip_bfloat16 b0 = __float2bfloat16(v.x), b1 = __float2bfloat16(v.y);
    __hip_bfloat16 b2 = __float2bfloat16(v.z), b3 = __float2bfloat16(v.w);
    o.x = *reinterpret_cast<ushort*>(&b0); o.y = *reinterpret_cast<ushort*>(&b1);
    o.z = *reinterpret_cast<ushort*>(&b2); o.w = *reinterpret_cast<ushort*>(&b3);
    *reinterpret_cast<ushort4*>(ebf + (size_t)row * NDIM + lane * 4) = o;
    float acc = v.x*v.x + v.y*v.y + v.z*v.z + v.w*v.w;
    #pragma unroll
    for (int off = 32; off > 0; off >>= 1) acc += __shfl_down(acc, off);
    if (lane == 0) sqn[row] = acc;
    cs.x += v.x; cs.y += v.y; cs.z += v.z; cs.w += v.w;
  }
  atomicAdd(&lcs[lane * 4 + 0], cs.x);
  atomicAdd(&lcs[lane * 4 + 1], cs.y);
  atomicAdd(&lcs[lane * 4 + 2], cs.z);
  atomicAdd(&lcs[lane * 4 + 3], cs.w);
  __syncthreads();
  pcs[blockIdx.x * NDIM + tid] = lcs[tid];
}

// Fused Gram + top-8, R=2 row-blocks per wave.
// Swapped 32x32x16 MFMA (D = jf * if): lane owns one i-row (col=lane&31).
// Each jf ds_read feeds TWO MFMAs (row-blocks A/B) -> LDS reads halved.
// LDS: K-major [kk][hi][col][16B] ^ ((kk&7)<<4); staged via global_load_lds
// (linear dest + inverse-swizzled per-lane source; 0-conflict, verified).
// Selection: min-tree + __any ballot-skip around the med3 insert network.
__launch_bounds__(256, 2)
__global__ void k_main(const ushort* __restrict__ eb,
                       const float* __restrict__ sqn,
                       float* __restrict__ knn_out,
                       int jrange, int jsplit) {
  __shared__ ushort lbuf[2][TCOL * NDIM];   // 2 x 16 KiB
  __shared__ float  lsqn[1024];

  const int tid  = threadIdx.x;
  const int lane = tid & 63;
  const int wv   = tid >> 6;
  const int col  = lane & 31;
  const int hi   = lane >> 5;
  const int rowA = blockIdx.x * BLK_ROWS + wv * 32 + col;
  const int rowB = rowA + 128;
  const int split = blockIdx.y;
  const int jbase = split * jrange;

  // i-fragments for both row-blocks (128 VGPRs).
  bf16x8 ifA[16], ifB[16];
  #pragma unroll
  for (int kk = 0; kk < 16; ++kk) {
    ifA[kk] = *reinterpret_cast<const bf16x8*>(eb + (size_t)rowA * NDIM + kk * 16 + hi * 8);
    ifB[kk] = *reinterpret_cast<const bf16x8*>(eb + (size_t)rowB * NDIM + kk * 16 + hi * 8);
  }
  const float niA = sqn[rowA];
  const float niB = sqn[rowB];

  float mA[KNN], mB[KNN];
  #pragma unroll
  for (int i = 0; i < KNN; ++i) { mA[i] = 1e30f; mB[i] = 1e30f; }

  for (int i = tid; i < jrange; i += 256) lsqn[i] = sqn[jbase + i];

  auto stage = [&](int bufi, int jb) {
    #pragma unroll
    for (int s = 0; s < 4; ++s) {
      const int o  = s * 4096 + wv * 1024 + lane * 16;   // linear LDS byte
      const int kk = o >> 10;
      const int h  = (o >> 9) & 1;
      const int c  = ((o & 511) ^ ((kk & 7) << 4)) >> 4; // inverse swizzle on SOURCE
      const ushort* src = eb + (size_t)(jb + c) * NDIM + (kk * 2 + h) * 8;
      __builtin_amdgcn_global_load_lds(
          (const __attribute__((address_space(1))) void*)src,
          (__attribute__((address_space(3))) void*)(
              reinterpret_cast<char*>(&lbuf[bufi][0]) + s * 4096 + wv * 1024),
          16, 0, 0);
    }
  };

  // selection for one row-block: candidates from acc, with ballot-skip.
  auto select = [&](const f32x16& acc, float* m, int jloc) {
    float c[16];
    #pragma unroll
    for (int g = 0; g < 4; ++g) {
      const float4 nj = *reinterpret_cast<const float4*>(&lsqn[jloc + g * 8 + hi * 4]);
      c[g*4+0] = fmaf(-2.0f, acc[g*4+0], nj.x);
      c[g*4+1] = fmaf(-2.0f, acc[g*4+1], nj.y);
      c[g*4+2] = fmaf(-2.0f, acc[g*4+2], nj.z);
      c[g*4+3] = fmaf(-2.0f, acc[g*4+3], nj.w);
    }
    float t0 = fminf(fminf(fminf(c[0], c[1]), fminf(c[2], c[3])),
                     fminf(fminf(c[4], c[5]), fminf(c[6], c[7])));
    float t1 = fminf(fminf(fminf(c[8], c[9]), fminf(c[10], c[11])),
                     fminf(fminf(c[12], c[13]), fminf(c[14], c[15])));
    if (__any(fminf(t0, t1) < m[7])) {
      #pragma unroll
      for (int q = 0; q < 16; ++q) {
        const float cc = c[q];
        m[7] = __builtin_amdgcn_fmed3f(m[6], m[7], cc);
        m[6] = __builtin_amdgcn_fmed3f(m[5], m[6], cc);
        m[5] = __builtin_amdgcn_fmed3f(m[4], m[5], cc);
        m[4] = __builtin_amdgcn_fmed3f(m[3], m[4], cc);
        m[3] = __builtin_amdgcn_fmed3f(m[2], m[3], cc);
        m[2] = __builtin_amdgcn_fmed3f(m[1], m[2], cc);
        m[1] = __builtin_amdgcn_fmed3f(m[0], m[1], cc);
        m[0] = fminf(m[0], cc);
      }
    }
  };

  stage(0, jbase);
  asm volatile("s_waitcnt vmcnt(0)" ::: "memory");
  __syncthreads();

  const int nT = jrange / TCOL;
  int buf = 0;
  for (int it = 0; it < nT; ++it) {
    if (it + 1 < nT) stage(buf ^ 1, jbase + (it + 1) * TCOL);

    f32x16 accA, accB;
    #pragma unroll
    for (int i = 0; i < 16; ++i) { accA[i] = 0.f; accB[i] = 0.f; }
    #pragma unroll
    for (int kk = 0; kk < 16; ++kk) {
      const int b0 = (kk * 1024 + hi * 512 + col * 16) ^ ((kk & 7) << 4);
      const bf16x8 jf = *reinterpret_cast<const bf16x8*>(
          reinterpret_cast<const char*>(&lbuf[buf][0]) + b0);
      accA = __builtin_amdgcn_mfma_f32_32x32x16_bf16(jf, ifA[kk], accA, 0, 0, 0);
      accB = __builtin_amdgcn_mfma_f32_32x32x16_bf16(jf, ifB[kk], accB, 0, 0, 0);
    }

    select(accA, mA, it * TCOL);
    select(accB, mB, it * TCOL);

    asm volatile("s_waitcnt vmcnt(0)" ::: "memory");
    __syncthreads();
    buf ^= 1;
  }

  // merge k-half lists (lane <-> lane+32): mins of two sorted-8 lists are
  // elementwise min(a_k, b_{7-k}); hi==0 lanes write.
  float g[KNN];
  #pragma unroll
  for (int k = 0; k < KNN; ++k)
    g[k] = fminf(mA[k], __shfl_xor(mA[KNN - 1 - k], 32));
  if (hi == 0) {
    float* dst = knn_out + ((size_t)split * NROWS + rowA) * KNN;
    #pragma unroll
    for (int k = 0; k < KNN; ++k) dst[k] = fmaxf(niA + g[k], 0.0f);
  }
  #pragma unroll
  for (int k = 0; k < KNN; ++k)
    g[k] = fminf(mB[k], __shfl_xor(mB[KNN - 1 - k], 32));
  if (hi == 0) {
    float* dst = knn_out + ((size_t)split * NROWS + rowB) * KNN;
    #pragma unroll
    for (int k = 0; k < KNN; ++k) dst[k] = fmaxf(niB + g[k], 0.0f);
  }
}

// Merge jsplit 8-sets per row; reduce sum8/S2; block 0 reduces colsum
// partials -> Q; last finishing block computes the output scalar.
__global__ void k_final(const float* __restrict__ knn,
                        const float* __restrict__ sqn,
                        const float* __restrict__ pcs,
                        float* __restrict__ gacc,
                        float* __restrict__ out, int jsplit) {
  const int tid = threadIdx.x;
  const int row = blockIdx.x * blockDim.x + tid;
  float m[KNN];
  #pragma unroll
  for (int i = 0; i < KNN; ++i) m[i] = 1e30f;
  for (int s = 0; s < jsplit; ++s) {
    const float* p = knn + ((size_t)s * NROWS + row) * KNN;
    #pragma unroll
    for (int i = 0; i < KNN; ++i) {
      const float c = p[i];
      m[7] = __builtin_amdgcn_fmed3f(m[6], m[7], c);
      m[6] = __builtin_amdgcn_fmed3f(m[5], m[6], c);
      m[5] = __builtin_amdgcn_fmed3f(m[4], m[5], c);
      m[4] = __builtin_amdgcn_fmed3f(m[3], m[4], c);
      m[3] = __builtin_amdgcn_fmed3f(m[2], m[3], c);
      m[2] = __builtin_amdgcn_fmed3f(m[1], m[2], c);
      m[1] = __builtin_amdgcn_fmed3f(m[0], m[1], c);
      m[0] = fminf(m[0], c);
    }
  }
  float rs = 0.f;
  #pragma unroll
  for (int i = 0; i < KNN; ++i) rs += m[i];
  float s2 = sqn[row];

  __shared__ float red[2][4];
  #pragma unroll
  for (int off = 32; off > 0; off >>= 1) {
    rs += __shfl_down(rs, off);
    s2 += __shfl_down(s2, off);
  }
  if ((tid & 63) == 0) { red[0][tid >> 6] = rs; red[1][tid >> 6] = s2; }
  __syncthreads();
  if (tid == 0) {
    atomicAdd(&gacc[0], red[0][0] + red[0][1] + red[0][2] + red[0][3]);
    atomicAdd(&gacc[1], red[1][0] + red[1][1] + red[1][2] + red[1][3]);
  }
  if (blockIdx.x == 0) {
    float s = 0.f;
    for (int b = 0; b < 128; ++b) s += pcs[b * NDIM + tid];
    float q = s * s;
    #pragma unroll
    for (int off = 32; off > 0; off >>= 1) q += __shfl_down(q, off);
    __syncthreads();
    if ((tid & 63) == 0) red[0][tid >> 6] = q;
    __syncthreads();
    if (tid == 0) atomicAdd(&gacc[2], red[0][0] + red[0][1] + red[0][2] + red[0][3]);
  }
  // completion: last block computes the output scalar.
  if (tid == 0) {
    __threadfence();
    int* cnt = (int*)(gacc + 3);
    const int prev = atomicAdd(cnt, 1);
    if (prev == (int)gridDim.x - 1) {
      const float sum8 = atomicAdd(&gacc[0], 0.0f);
      const float S2   = atomicAdd(&gacc[1], 0.0f);
      const float Q    = atomicAdd(&gacc[2], 0.0f);
      const float ref_var = (S2 - Q / (float)NROWS) / ((float)NDIM * (float)(NROWS - 1));
      out[0] = (sum8 / (float)(NROWS * KNN)) / ref_var;
    }
  }
}

extern "C" void kernel_launch(void* const* d_in, const int* in_sizes, int n_in,
                              void* d_out, int out_size, void* d_ws, size_t ws_size,
                              hipStream_t stream) {
  const float* e = (const float*)d_in[0];
  char* ws = (char*)d_ws;
  ushort* ebf = (ushort*)(ws + WS_EBF);
  float* sqn  = (float*)(ws + WS_SQN);
  float* pcs  = (float*)(ws + WS_PCS);
  float* gacc = (float*)(ws + WS_ACC);
  float* knn  = (float*)(ws + WS_KNN);
  float* out  = (float*)d_out;

  const size_t need16 = (size_t)WS_KNN + (size_t)NROWS * 16 * KNN * 4;
  const int jsplit = (ws_size >= need16) ? 16 : 8;
  const int jrange = NROWS / jsplit;

  hipLaunchKernelGGL(k_prep,  dim3(128), dim3(256), 0, stream, e, ebf, sqn, pcs, gacc);
  hipLaunchKernelGGL(k_main,  dim3(NROWS / BLK_ROWS, jsplit), dim3(256), 0, stream,
                     ebf, sqn, knn, jrange, jsplit);
  hipLaunchKernelGGL(k_final, dim3(NROWS / 256), dim3(256), 0, stream,
                     knn, sqn, pcs, gacc, out, jsplit);
}